// Round 2
// baseline (580.397 us; speedup 1.0000x reference)
//
#include <hip/hip_runtime.h>

typedef __bf16 bfrag __attribute__((ext_vector_type(8)));
typedef float f32x4 __attribute__((ext_vector_type(4)));

#define GLDS16(g, l) __builtin_amdgcn_global_load_lds( \
    (__attribute__((address_space(1))) void*)(g),      \
    (__attribute__((address_space(3))) void*)(l), 16, 0, 0)

__device__ __forceinline__ float bf2f(ushort u) {
    return __uint_as_float(((unsigned)u) << 16);
}
__device__ __forceinline__ ushort f2bf(float f) {
    unsigned u = __float_as_uint(f);
    u += 0x7fff + ((u >> 16) & 1);
    return (ushort)(u >> 16);
}
__device__ __forceinline__ float sigmoidf_(float v) {
    return 1.0f / (1.0f + expf(-v));
}

// ---------------- cast+concat: xhcb[b][0:3072] = bf16([x|h|c][b]) ----------------
__global__ __launch_bounds__(256) void k_castcat(const float* __restrict__ x,
                                                 const float* __restrict__ h,
                                                 const float* __restrict__ c,
                                                 ushort* __restrict__ xhcb) {
    int idx = blockIdx.x * 256 + threadIdx.x;  // 3,145,728 total, 8 elems each
    int row = idx / 384;
    int c8 = (idx - row * 384) * 8;
    const float* s = (c8 < 1024) ? &x[(size_t)row * 1024 + c8]
                   : (c8 < 2048) ? &h[(size_t)row * 1024 + (c8 - 1024)]
                                 : &c[(size_t)row * 1024 + (c8 - 2048)];
    float4 a = *(const float4*)s;
    float4 b = *(const float4*)(s + 4);
    ushort tmp[8] = {f2bf(a.x), f2bf(a.y), f2bf(a.z), f2bf(a.w),
                     f2bf(b.x), f2bf(b.y), f2bf(b.z), f2bf(b.w)};
    *(uint4*)&xhcb[(size_t)idx * 8] = *(uint4*)tmp;
}

// ---------------- transpose+cast: dst_bf16[n*dst_ld + k] = src_f32[k*1024 + n] ----
__global__ __launch_bounds__(256) void k_transW(const float* __restrict__ src,
                                                ushort* __restrict__ dst, int dst_ld) {
    __shared__ float tile[64][65];
    int k0 = blockIdx.x * 64, n0 = blockIdx.y * 64;
    int t = threadIdx.x;
    int c4 = (t & 15) * 4;  // 0..60
    int r = t >> 4;         // 0..15
#pragma unroll
    for (int i = 0; i < 4; ++i) {
        int rr = r + i * 16;
        float4 v = *(const float4*)&src[(size_t)(k0 + rr) * 1024 + n0 + c4];
        tile[rr][c4 + 0] = v.x; tile[rr][c4 + 1] = v.y;
        tile[rr][c4 + 2] = v.z; tile[rr][c4 + 3] = v.w;
    }
    __syncthreads();
    int kk8 = (t & 7) * 8;  // 0..56
    int nn = t >> 3;        // 0..31
#pragma unroll
    for (int i = 0; i < 2; ++i) {
        int n = nn + i * 32;
        ushort tmp[8];
#pragma unroll
        for (int j = 0; j < 8; ++j) tmp[j] = f2bf(tile[kk8 + j][n]);
        *(uint4*)&dst[(size_t)(n0 + n) * dst_ld + k0 + kk8] = *(uint4*)tmp;
    }
}

// ---------------- concat biases (f32) into [4096] ----------------
__global__ void k_biasf(const float* bi, const float* bf_, const float* bc,
                        const float* bo, float* dst) {
    int t = blockIdx.x * 256 + threadIdx.x;  // 0..4095
    int g = t >> 10, n = t & 1023;
    const float* s = (g == 0) ? bi : (g == 1) ? bf_ : (g == 2) ? bc : bo;
    dst[t] = s[n];
}

// ---------------- GEMM1: Pre[b][0:4096] = xhc @ [W_i|W_f|W_cand|W_o(:2048)] + bias ----
__global__ __launch_bounds__(256) void k_gemm1(const ushort* __restrict__ xhcb,
                                               const ushort* __restrict__ WT,
                                               const float* __restrict__ bias,
                                               ushort* __restrict__ Pre) {
    __shared__ __align__(16) ushort As[128 * 32];
    __shared__ __align__(16) ushort Bs[128 * 32];
    int t = threadIdx.x;
    int m0 = blockIdx.x * 128, n0 = blockIdx.y * 128;
    int Kext = (n0 >= 2048) ? 2048 : 3072;
    int w = t >> 6, l = t & 63;
    int wm = (w & 1) * 64, wn = (w >> 1) * 64;
    int lane16 = l & 15, quad = l >> 4;
    int sr = t >> 2;       // staging row 0..63
    int sk = (t & 3) * 8;  // staging k offset
    f32x4 acc[4][4] = {};

    for (int k0 = 0; k0 < Kext; k0 += 32) {
        GLDS16(xhcb + (size_t)(m0 + sr) * 3072 + k0 + sk,       As + t * 8);
        GLDS16(xhcb + (size_t)(m0 + sr + 64) * 3072 + k0 + sk,  As + 2048 + t * 8);
        GLDS16(WT + (size_t)(n0 + sr) * 3072 + k0 + sk,         Bs + t * 8);
        GLDS16(WT + (size_t)(n0 + sr + 64) * 3072 + k0 + sk,    Bs + 2048 + t * 8);
        __syncthreads();
        bfrag af[4], bfr[4];
#pragma unroll
        for (int i = 0; i < 4; ++i) {
            af[i]  = *(const bfrag*)&As[(wm + i * 16 + lane16) * 32 + quad * 8];
            bfr[i] = *(const bfrag*)&Bs[(wn + i * 16 + lane16) * 32 + quad * 8];
        }
#pragma unroll
        for (int i = 0; i < 4; ++i)
#pragma unroll
            for (int j = 0; j < 4; ++j)
                acc[i][j] = __builtin_amdgcn_mfma_f32_16x16x32_bf16(af[i], bfr[j], acc[i][j], 0, 0, 0);
        __syncthreads();
    }
#pragma unroll
    for (int i = 0; i < 4; ++i) {
#pragma unroll
        for (int j = 0; j < 4; ++j) {
            int col = n0 + wn + j * 16 + lane16;
            float bv = bias[col];
            int rbase = m0 + wm + i * 16 + quad * 4;
#pragma unroll
            for (int r = 0; r < 4; ++r)
                Pre[(size_t)(rbase + r) * 4096 + col] = f2bf(acc[i][j][r] + bv);
        }
    }
}

// ---------------- c_new = sigmoid(f)*c + sigmoid(i)*tanh(cand); f32 out + bf16 copy ----
__global__ __launch_bounds__(256) void k_cnew(const ushort* __restrict__ Pre,
                                              const float* __restrict__ cin,
                                              ushort* __restrict__ Cnewb,
                                              float* __restrict__ out) {
    int idx8 = blockIdx.x * 256 + threadIdx.x;  // 1,048,576 total
    int b = idx8 >> 7;
    int n8 = (idx8 & 127) * 8;
    uint4 vi = *(const uint4*)(Pre + (size_t)b * 4096 + n8);
    uint4 vf = *(const uint4*)(Pre + (size_t)b * 4096 + 1024 + n8);
    uint4 vc = *(const uint4*)(Pre + (size_t)b * 4096 + 2048 + n8);
    float4 c0 = *(const float4*)(cin + (size_t)b * 1024 + n8);
    float4 c1 = *(const float4*)(cin + (size_t)b * 1024 + n8 + 4);
    const ushort* pi = (const ushort*)&vi;
    const ushort* pf = (const ushort*)&vf;
    const ushort* pc = (const ushort*)&vc;
    float cv[8] = {c0.x, c0.y, c0.z, c0.w, c1.x, c1.y, c1.z, c1.w};
    float cn[8];
    ushort cb[8];
#pragma unroll
    for (int j = 0; j < 8; ++j) {
        float iv = sigmoidf_(bf2f(pi[j]));
        float fv = sigmoidf_(bf2f(pf[j]));
        float cp = tanhf(bf2f(pc[j]));
        cn[j] = fv * cv[j] + iv * cp;
        cb[j] = f2bf(cn[j]);
    }
    *(uint4*)(Cnewb + (size_t)b * 1024 + n8) = *(uint4*)cb;
    float* orow = out + (size_t)b * 2050 + 1024 + n8;  // 8B-aligned
#pragma unroll
    for (int j = 0; j < 4; ++j)
        *(float2*)(orow + j * 2) = make_float2(cn[j * 2], cn[j * 2 + 1]);
}

// ---------------- GEMM2: o_pre = Pre_o + c_new @ W_o[2048:]; h_new = sig(o)*tanh(c_new)
__global__ __launch_bounds__(256) void k_gemm2(const ushort* __restrict__ Cnewb,
                                               const ushort* __restrict__ WoCT,
                                               const ushort* __restrict__ Pre,
                                               float* __restrict__ out) {
    __shared__ __align__(16) ushort As[128 * 32];
    __shared__ __align__(16) ushort Bs[128 * 32];
    int t = threadIdx.x;
    int m0 = blockIdx.x * 128, n0 = blockIdx.y * 128;
    int w = t >> 6, l = t & 63;
    int wm = (w & 1) * 64, wn = (w >> 1) * 64;
    int lane16 = l & 15, quad = l >> 4;
    int sr = t >> 2;
    int sk = (t & 3) * 8;
    f32x4 acc[4][4] = {};

    for (int k0 = 0; k0 < 1024; k0 += 32) {
        GLDS16(Cnewb + (size_t)(m0 + sr) * 1024 + k0 + sk,       As + t * 8);
        GLDS16(Cnewb + (size_t)(m0 + sr + 64) * 1024 + k0 + sk,  As + 2048 + t * 8);
        GLDS16(WoCT + (size_t)(n0 + sr) * 1024 + k0 + sk,        Bs + t * 8);
        GLDS16(WoCT + (size_t)(n0 + sr + 64) * 1024 + k0 + sk,   Bs + 2048 + t * 8);
        __syncthreads();
        bfrag af[4], bfr[4];
#pragma unroll
        for (int i = 0; i < 4; ++i) {
            af[i]  = *(const bfrag*)&As[(wm + i * 16 + lane16) * 32 + quad * 8];
            bfr[i] = *(const bfrag*)&Bs[(wn + i * 16 + lane16) * 32 + quad * 8];
        }
#pragma unroll
        for (int i = 0; i < 4; ++i)
#pragma unroll
            for (int j = 0; j < 4; ++j)
                acc[i][j] = __builtin_amdgcn_mfma_f32_16x16x32_bf16(af[i], bfr[j], acc[i][j], 0, 0, 0);
        __syncthreads();
    }
#pragma unroll
    for (int i = 0; i < 4; ++i) {
#pragma unroll
        for (int j = 0; j < 4; ++j) {
            int col = n0 + wn + j * 16 + lane16;
            int rbase = m0 + wm + i * 16 + quad * 4;
#pragma unroll
            for (int r = 0; r < 4; ++r) {
                int row = rbase + r;
                float opre = acc[i][j][r] + bf2f(Pre[(size_t)row * 4096 + 3072 + col]);
                float o = sigmoidf_(opre);
                float cnv = bf2f(Cnewb[(size_t)row * 1024 + col]);
                out[(size_t)row * 2050 + col] = o * tanhf(cnv);
            }
        }
    }
}

// ---------------- attention + gumbel + alpha/beta (16 rows per block, f32) ----------------
__global__ __launch_bounds__(256) void k_attn(
    const float* __restrict__ outr, const float* __restrict__ x,
    const float* __restrict__ memory, const float* __restrict__ u_gs,
    const float* __restrict__ u_a, const float* __restrict__ u_b,
    const float* __restrict__ W_m, const float* __restrict__ b_m,
    const float* __restrict__ w_a_h, const float* __restrict__ w_a_x,
    const float* __restrict__ w_a_r, const float* __restrict__ w_b_h,
    const float* __restrict__ w_b_x, const float* __restrict__ w_b_r,
    float* __restrict__ out) {
    __shared__ float sWm[128 * 64];   // 32 KB
    __shared__ float sH[16 * 128];    // 8 KB
    __shared__ float sMicro[16 * 64];
    __shared__ float sAttn[16 * 16];
    __shared__ float sSamp[16 * 64];

    int b0 = blockIdx.x * 16;
    int t = threadIdx.x;
    int j = t & 63, g = t >> 6;

    // micro = h_new @ W_m + b_m   (h_new read from out[:, 0:1024])
    float acc[4] = {0.f, 0.f, 0.f, 0.f};
    for (int kc = 0; kc < 1024; kc += 128) {
#pragma unroll
        for (int i = 0; i < 8; ++i) {
            int e = (i * 256 + t) * 4;  // 0..8188
            *(float4*)&sWm[e] = *(const float4*)&W_m[(size_t)(kc + (e >> 6)) * 64 + (e & 63)];
        }
        {
            int r = t >> 4, cc = (t & 15) * 8;
            const float* src = &outr[(size_t)(b0 + r) * 2050 + kc + cc];
            float* d = &sH[r * 128 + cc];
#pragma unroll
            for (int q = 0; q < 4; ++q) {
                float2 v = *(const float2*)(src + q * 2);
                d[q * 2] = v.x; d[q * 2 + 1] = v.y;
            }
        }
        __syncthreads();
        for (int k = 0; k < 128; ++k) {
            float wm = sWm[k * 64 + j];
#pragma unroll
            for (int q = 0; q < 4; ++q)
                acc[q] += sH[(g * 4 + q) * 128 + k] * wm;
        }
        __syncthreads();
    }
    {
        float bm = b_m[j];
#pragma unroll
        for (int q = 0; q < 4; ++q) sMicro[(g * 4 + q) * 64 + j] = acc[q] + bm;
    }
    __syncthreads();

    // logits + gumbel softmax over M=16
    {
        int r = t >> 4, m = t & 15;
        const float* mem = memory + (size_t)(b0 + r) * 1024 + m * 64;
        float lg = 0.f;
        for (int k = 0; k < 64; ++k) lg += mem[k] * sMicro[r * 64 + k];
        float u = u_gs[(b0 + r) * 16 + m];   // f32 in [1e-6, 1-1e-6]: no clamp
        float z = lg + (-logf(-logf(u)));    // TAU = 1
        float zm = z;
        for (int off = 8; off; off >>= 1) zm = fmaxf(zm, __shfl_xor(zm, off, 16));
        float p = expf(z - zm);
        float ps = p;
        for (int off = 8; off; off >>= 1) ps += __shfl_xor(ps, off, 16);
        sAttn[r * 16 + m] = p / ps;
    }
    __syncthreads();

    // sampled = memory^T @ attn + 1
#pragma unroll
    for (int q = 0; q < 4; ++q) {
        int r = g * 4 + q;
        const float* mem = memory + (size_t)(b0 + r) * 1024 + j;
        float s = 0.f;
#pragma unroll
        for (int m = 0; m < 16; ++m) s += sAttn[r * 16 + m] * mem[m * 64];
        sSamp[r * 64 + j] = s + 1.0f;
    }
    __syncthreads();

    // alpha / beta
    {
        int r = t >> 4, s16 = t & 15;
        size_t hoff = (size_t)(b0 + r) * 2050;
        size_t xoff = (size_t)(b0 + r) * 1024;
        float za = 0.f, zb = 0.f;
        for (int kk = 0; kk < 64; ++kk) {
            int k = s16 + kk * 16;  // coalesced within 16-lane group
            float hv = outr[hoff + k];
            float xv = x[xoff + k];
            za += hv * w_a_h[k] + xv * w_a_x[k];
            zb += hv * w_b_h[k] + xv * w_b_x[k];
        }
#pragma unroll
        for (int k = s16 * 4; k < s16 * 4 + 4; ++k) {
            float sv = sSamp[r * 64 + k];
            za += sv * w_a_r[k];
            zb += sv * w_b_r[k];
        }
        for (int off = 8; off; off >>= 1) {
            za += __shfl_xor(za, off, 16);
            zb += __shfl_xor(zb, off, 16);
        }
        if (s16 == 0) {
            float ua = u_a[b0 + r];
            float ub = u_b[b0 + r];
            float la = logf(ua) - log1pf(-ua);
            float lb = logf(ub) - log1pf(-ub);
            out[(size_t)(b0 + r) * 2050 + 2048] = sigmoidf_(za + la);
            out[(size_t)(b0 + r) * 2050 + 2049] = sigmoidf_(zb + lb);
        }
    }
}

extern "C" void kernel_launch(void* const* d_in, const int* in_sizes, int n_in,
                              void* d_out, int out_size, void* d_ws, size_t ws_size,
                              hipStream_t stream) {
    const float* x      = (const float*)d_in[0];
    const float* h      = (const float*)d_in[1];
    const float* c      = (const float*)d_in[2];
    const float* memory = (const float*)d_in[3];
    const float* u_gs   = (const float*)d_in[4];
    const float* u_a    = (const float*)d_in[5];
    const float* u_b    = (const float*)d_in[6];
    const float* W_i    = (const float*)d_in[7];
    const float* b_i    = (const float*)d_in[8];
    const float* W_f    = (const float*)d_in[9];
    const float* b_f    = (const float*)d_in[10];
    const float* W_o    = (const float*)d_in[11];
    const float* b_o    = (const float*)d_in[12];
    const float* W_cand = (const float*)d_in[13];
    const float* b_cand = (const float*)d_in[14];
    const float* W_m    = (const float*)d_in[15];
    const float* b_m    = (const float*)d_in[16];
    const float* w_a_h  = (const float*)d_in[17];
    const float* w_a_x  = (const float*)d_in[18];
    const float* w_a_r  = (const float*)d_in[19];
    const float* w_b_h  = (const float*)d_in[20];
    const float* w_b_x  = (const float*)d_in[21];
    const float* w_b_r  = (const float*)d_in[22];
    float* out = (float*)d_out;

    // workspace carve (bytes): WT 25.2M | WoCT 2.1M | Pre 67.1M | xhcb 50.3M | Biasf
    char* ws = (char*)d_ws;
    ushort* WT    = (ushort*)(ws);
    ushort* WoCT  = (ushort*)(ws + 25165824);
    ushort* Pre   = (ushort*)(ws + 27262976);
    ushort* xhcb  = (ushort*)(ws + 94371840);
    float*  Biasf = (float*)(ws + 144703488);
    ushort* Cnewb = xhcb;  // alias: xhcb dead after k_gemm1

    k_castcat<<<12288, 256, 0, stream>>>(x, h, c, xhcb);
    k_transW<<<dim3(48, 16), 256, 0, stream>>>(W_i, WT, 3072);
    k_transW<<<dim3(48, 16), 256, 0, stream>>>(W_f, WT + (size_t)1024 * 3072, 3072);
    k_transW<<<dim3(32, 16), 256, 0, stream>>>(W_cand, WT + (size_t)2048 * 3072, 3072);
    k_transW<<<dim3(32, 16), 256, 0, stream>>>(W_o, WT + (size_t)3072 * 3072, 3072);
    k_transW<<<dim3(16, 16), 256, 0, stream>>>(W_o + (size_t)2048 * 1024, WoCT, 1024);
    k_biasf<<<16, 256, 0, stream>>>(b_i, b_f, b_cand, b_o, Biasf);

    k_gemm1<<<dim3(64, 32), 256, 0, stream>>>(xhcb, WT, Biasf, Pre);
    k_cnew<<<4096, 256, 0, stream>>>(Pre, c, Cnewb, out);
    k_gemm2<<<dim3(64, 8), 256, 0, stream>>>(Cnewb, WoCT, Pre, out);
    k_attn<<<512, 256, 0, stream>>>(out, x, memory, u_gs, u_a, u_b, W_m, b_m,
                                    w_a_h, w_a_x, w_a_r, w_b_h, w_b_x, w_b_r, out);
}

// Round 3
// 572.039 us; speedup vs baseline: 1.0146x; 1.0146x over previous
//
#include <hip/hip_runtime.h>

typedef __bf16 bfrag __attribute__((ext_vector_type(8)));
typedef float f32x4 __attribute__((ext_vector_type(4)));

#define GLDS16(g, l) __builtin_amdgcn_global_load_lds( \
    (__attribute__((address_space(1))) void*)(g),      \
    (__attribute__((address_space(3))) void*)(l), 16, 0, 0)

__device__ __forceinline__ float bf2f(ushort u) {
    return __uint_as_float(((unsigned)u) << 16);
}
__device__ __forceinline__ ushort f2bf(float f) {
    unsigned u = __float_as_uint(f);
    u += 0x7fff + ((u >> 16) & 1);
    return (ushort)(u >> 16);
}
__device__ __forceinline__ float sigmoidf_(float v) {
    return 1.0f / (1.0f + expf(-v));
}

// ---------------- cast+concat: xhcb[b][0:3072] = bf16([x|h|c][b]) ----------------
__global__ __launch_bounds__(256) void k_castcat(const float* __restrict__ x,
                                                 const float* __restrict__ h,
                                                 const float* __restrict__ c,
                                                 ushort* __restrict__ xhcb) {
    int idx = blockIdx.x * 256 + threadIdx.x;  // 3,145,728 total, 8 elems each
    int row = idx / 384;
    int c8 = (idx - row * 384) * 8;
    const float* s = (c8 < 1024) ? &x[(size_t)row * 1024 + c8]
                   : (c8 < 2048) ? &h[(size_t)row * 1024 + (c8 - 1024)]
                                 : &c[(size_t)row * 1024 + (c8 - 2048)];
    float4 a = *(const float4*)s;
    float4 b = *(const float4*)(s + 4);
    ushort tmp[8] = {f2bf(a.x), f2bf(a.y), f2bf(a.z), f2bf(a.w),
                     f2bf(b.x), f2bf(b.y), f2bf(b.z), f2bf(b.w)};
    *(uint4*)&xhcb[(size_t)idx * 8] = *(uint4*)tmp;
}

// ---------------- combined transpose+cast of all weights ----------------
struct TD { const float* src; ushort* dst; int src_ld; int dst_ld; int ktiles; int off; };
struct TA { TD d[6]; };

__global__ __launch_bounds__(256) void k_transAll(TA a) {
    __shared__ float tile[64][65];
    int bid = blockIdx.x;
    int ri = 0;
#pragma unroll
    for (int i = 1; i < 6; ++i) ri = (bid >= a.d[i].off) ? i : ri;
    const float* src = a.d[ri].src;
    ushort* dst = a.d[ri].dst;
    int src_ld = a.d[ri].src_ld, dst_ld = a.d[ri].dst_ld;
    int local = bid - a.d[ri].off;
    int bx = local % a.d[ri].ktiles;
    int by = local / a.d[ri].ktiles;
    int k0 = bx * 64, n0 = by * 64;
    int t = threadIdx.x;
    int c4 = (t & 15) * 4;  // 0..60
    int r = t >> 4;         // 0..15
#pragma unroll
    for (int i = 0; i < 4; ++i) {
        int rr = r + i * 16;
        float4 v = *(const float4*)&src[(size_t)(k0 + rr) * src_ld + n0 + c4];
        tile[rr][c4 + 0] = v.x; tile[rr][c4 + 1] = v.y;
        tile[rr][c4 + 2] = v.z; tile[rr][c4 + 3] = v.w;
    }
    __syncthreads();
    int kk8 = (t & 7) * 8;  // 0..56
    int nn = t >> 3;        // 0..31
#pragma unroll
    for (int i = 0; i < 2; ++i) {
        int n = nn + i * 32;
        ushort tmp[8];
#pragma unroll
        for (int j = 0; j < 8; ++j) tmp[j] = f2bf(tile[kk8 + j][n]);
        *(uint4*)&dst[(size_t)(n0 + n) * dst_ld + k0 + kk8] = *(uint4*)tmp;
    }
}

// ---------------- concat biases (f32) into [4096] ----------------
__global__ void k_biasf(const float* bi, const float* bf_, const float* bc,
                        const float* bo, float* dst) {
    int t = blockIdx.x * 256 + threadIdx.x;  // 0..4095
    int g = t >> 10, n = t & 1023;
    const float* s = (g == 0) ? bi : (g == 1) ? bf_ : (g == 2) ? bc : bo;
    dst[t] = s[n];
}

// ---------------- GEMM1: Pre[b][0:4096] = xhc @ [W_i|W_f|W_cand|W_o(:2048)] + bias ----
// LDS bank-conflict swizzle: logical k-group kg stored at slot kg ^ ((row>>1)&3).
__global__ __launch_bounds__(256) void k_gemm1(const ushort* __restrict__ xhcb,
                                               const ushort* __restrict__ WT,
                                               const float* __restrict__ bias,
                                               ushort* __restrict__ Pre) {
    __shared__ __align__(16) ushort As[128 * 32];
    __shared__ __align__(16) ushort Bs[128 * 32];
    int t = threadIdx.x;
    int m0 = blockIdx.x * 128, n0 = blockIdx.y * 128;
    int Kext = (n0 >= 2048) ? 2048 : 3072;
    int w = t >> 6, l = t & 63;
    int wm = (w & 1) * 64, wn = (w >> 1) * 64;
    int lane16 = l & 15, quad = l >> 4;
    int sr = t >> 2;                                  // staging row 0..63
    int sko = (((t & 3) ^ ((sr >> 1) & 3))) * 8;      // swizzled source k-offset
    int sw8 = ((lane16 >> 1) & 3) * 8;                // read-side swizzle
    f32x4 acc[4][4] = {};

    for (int k0 = 0; k0 < Kext; k0 += 32) {
        GLDS16(xhcb + (size_t)(m0 + sr) * 3072 + k0 + sko,       As + t * 8);
        GLDS16(xhcb + (size_t)(m0 + sr + 64) * 3072 + k0 + sko,  As + 2048 + t * 8);
        GLDS16(WT + (size_t)(n0 + sr) * 3072 + k0 + sko,         Bs + t * 8);
        GLDS16(WT + (size_t)(n0 + sr + 64) * 3072 + k0 + sko,    Bs + 2048 + t * 8);
        __syncthreads();
        bfrag af[4], bfr[4];
#pragma unroll
        for (int i = 0; i < 4; ++i) {
            af[i]  = *(const bfrag*)&As[(wm + i * 16 + lane16) * 32 + ((quad * 8) ^ sw8)];
            bfr[i] = *(const bfrag*)&Bs[(wn + i * 16 + lane16) * 32 + ((quad * 8) ^ sw8)];
        }
#pragma unroll
        for (int i = 0; i < 4; ++i)
#pragma unroll
            for (int j = 0; j < 4; ++j)
                acc[i][j] = __builtin_amdgcn_mfma_f32_16x16x32_bf16(af[i], bfr[j], acc[i][j], 0, 0, 0);
        __syncthreads();
    }
#pragma unroll
    for (int i = 0; i < 4; ++i) {
#pragma unroll
        for (int j = 0; j < 4; ++j) {
            int col = n0 + wn + j * 16 + lane16;
            float bv = bias[col];
            int rbase = m0 + wm + i * 16 + quad * 4;
#pragma unroll
            for (int r = 0; r < 4; ++r)
                Pre[(size_t)(rbase + r) * 4096 + col] = f2bf(acc[i][j][r] + bv);
        }
    }
}

// ---------------- c_new = sigmoid(f)*c + sigmoid(i)*tanh(cand); f32 out + bf16 copy ----
__global__ __launch_bounds__(256) void k_cnew(const ushort* __restrict__ Pre,
                                              const float* __restrict__ cin,
                                              ushort* __restrict__ Cnewb,
                                              float* __restrict__ out) {
    int idx8 = blockIdx.x * 256 + threadIdx.x;  // 1,048,576 total
    int b = idx8 >> 7;
    int n8 = (idx8 & 127) * 8;
    uint4 vi = *(const uint4*)(Pre + (size_t)b * 4096 + n8);
    uint4 vf = *(const uint4*)(Pre + (size_t)b * 4096 + 1024 + n8);
    uint4 vc = *(const uint4*)(Pre + (size_t)b * 4096 + 2048 + n8);
    float4 c0 = *(const float4*)(cin + (size_t)b * 1024 + n8);
    float4 c1 = *(const float4*)(cin + (size_t)b * 1024 + n8 + 4);
    const ushort* pi = (const ushort*)&vi;
    const ushort* pf = (const ushort*)&vf;
    const ushort* pc = (const ushort*)&vc;
    float cv[8] = {c0.x, c0.y, c0.z, c0.w, c1.x, c1.y, c1.z, c1.w};
    float cn[8];
    ushort cb[8];
#pragma unroll
    for (int j = 0; j < 8; ++j) {
        float iv = sigmoidf_(bf2f(pi[j]));
        float fv = sigmoidf_(bf2f(pf[j]));
        float cp = tanhf(bf2f(pc[j]));
        cn[j] = fv * cv[j] + iv * cp;
        cb[j] = f2bf(cn[j]);
    }
    *(uint4*)(Cnewb + (size_t)b * 1024 + n8) = *(uint4*)cb;
    float* orow = out + (size_t)b * 2050 + 1024 + n8;  // 8B-aligned
#pragma unroll
    for (int j = 0; j < 4; ++j)
        *(float2*)(orow + j * 2) = make_float2(cn[j * 2], cn[j * 2 + 1]);
}

// ---------------- GEMM2: o_pre = Pre_o + c_new @ W_o[2048:]; h_new = sig(o)*tanh(c_new)
__global__ __launch_bounds__(256) void k_gemm2(const ushort* __restrict__ Cnewb,
                                               const ushort* __restrict__ WoCT,
                                               const ushort* __restrict__ Pre,
                                               ushort* __restrict__ Hnewb,
                                               float* __restrict__ out) {
    __shared__ __align__(16) ushort As[128 * 32];
    __shared__ __align__(16) ushort Bs[128 * 32];
    int t = threadIdx.x;
    int m0 = blockIdx.x * 128, n0 = blockIdx.y * 128;
    int w = t >> 6, l = t & 63;
    int wm = (w & 1) * 64, wn = (w >> 1) * 64;
    int lane16 = l & 15, quad = l >> 4;
    int sr = t >> 2;
    int sko = (((t & 3) ^ ((sr >> 1) & 3))) * 8;
    int sw8 = ((lane16 >> 1) & 3) * 8;
    f32x4 acc[4][4] = {};

    for (int k0 = 0; k0 < 1024; k0 += 32) {
        GLDS16(Cnewb + (size_t)(m0 + sr) * 1024 + k0 + sko,       As + t * 8);
        GLDS16(Cnewb + (size_t)(m0 + sr + 64) * 1024 + k0 + sko,  As + 2048 + t * 8);
        GLDS16(WoCT + (size_t)(n0 + sr) * 1024 + k0 + sko,        Bs + t * 8);
        GLDS16(WoCT + (size_t)(n0 + sr + 64) * 1024 + k0 + sko,   Bs + 2048 + t * 8);
        __syncthreads();
        bfrag af[4], bfr[4];
#pragma unroll
        for (int i = 0; i < 4; ++i) {
            af[i]  = *(const bfrag*)&As[(wm + i * 16 + lane16) * 32 + ((quad * 8) ^ sw8)];
            bfr[i] = *(const bfrag*)&Bs[(wn + i * 16 + lane16) * 32 + ((quad * 8) ^ sw8)];
        }
#pragma unroll
        for (int i = 0; i < 4; ++i)
#pragma unroll
            for (int j = 0; j < 4; ++j)
                acc[i][j] = __builtin_amdgcn_mfma_f32_16x16x32_bf16(af[i], bfr[j], acc[i][j], 0, 0, 0);
        __syncthreads();
    }
#pragma unroll
    for (int i = 0; i < 4; ++i) {
#pragma unroll
        for (int j = 0; j < 4; ++j) {
            int col = n0 + wn + j * 16 + lane16;
            int rbase = m0 + wm + i * 16 + quad * 4;
#pragma unroll
            for (int r = 0; r < 4; ++r) {
                int row = rbase + r;
                float opre = acc[i][j][r] + bf2f(Pre[(size_t)row * 4096 + 3072 + col]);
                float o = sigmoidf_(opre);
                float cnv = bf2f(Cnewb[(size_t)row * 1024 + col]);
                float hv = o * tanhf(cnv);
                Hnewb[(size_t)row * 1024 + col] = f2bf(hv);
                out[(size_t)row * 2050 + col] = hv;
            }
        }
    }
}

// ---------------- attention + gumbel + alpha/beta (16 rows per block) ----------------
// micro = h_new @ W_m via per-wave MFMA (A from Hnewb bf16, B from WmT bf16)
__global__ __launch_bounds__(256) void k_attn(
    const ushort* __restrict__ Hnewb, const float* __restrict__ outr,
    const float* __restrict__ x, const float* __restrict__ memory,
    const float* __restrict__ u_gs, const float* __restrict__ u_a,
    const float* __restrict__ u_b, const ushort* __restrict__ WmT,
    const float* __restrict__ b_m,
    const float* __restrict__ w_a_h, const float* __restrict__ w_a_x,
    const float* __restrict__ w_a_r, const float* __restrict__ w_b_h,
    const float* __restrict__ w_b_x, const float* __restrict__ w_b_r,
    float* __restrict__ out) {
    __shared__ float sMicro[16 * 64];
    __shared__ float sAttn[16 * 16];
    __shared__ float sSamp[16 * 64];

    int b0 = blockIdx.x * 16;
    int t = threadIdx.x;
    int w = t >> 6, l = t & 63;
    int lane16 = l & 15, quad = l >> 4;

    // wave w computes micro[0:16][16w:16w+16]
    {
        f32x4 acc = {0.f, 0.f, 0.f, 0.f};
        const ushort* Ab = Hnewb + (size_t)(b0 + lane16) * 1024 + quad * 8;
        const ushort* Bb = WmT + (size_t)(w * 16 + lane16) * 1024 + quad * 8;
#pragma unroll 4
        for (int k0 = 0; k0 < 1024; k0 += 32) {
            bfrag av = *(const bfrag*)(Ab + k0);
            bfrag bv = *(const bfrag*)(Bb + k0);
            acc = __builtin_amdgcn_mfma_f32_16x16x32_bf16(av, bv, acc, 0, 0, 0);
        }
        float bm = b_m[w * 16 + lane16];
#pragma unroll
        for (int r = 0; r < 4; ++r)
            sMicro[(quad * 4 + r) * 64 + w * 16 + lane16] = acc[r] + bm;
    }
    __syncthreads();

    // logits + gumbel softmax over M=16
    {
        int r = t >> 4, m = t & 15;
        const float4* mem4 = (const float4*)(memory + (size_t)(b0 + r) * 1024 + m * 64);
        float lg = 0.f;
#pragma unroll
        for (int k4 = 0; k4 < 16; ++k4) {
            float4 mv = mem4[k4];
            const float* sm = &sMicro[r * 64 + k4 * 4];
            lg += mv.x * sm[0] + mv.y * sm[1] + mv.z * sm[2] + mv.w * sm[3];
        }
        float u = u_gs[(b0 + r) * 16 + m];   // f32 in [1e-6, 1-1e-6]: no clamp
        float z = lg - logf(-logf(u));       // TAU = 1
        float zm = z;
        for (int off = 8; off; off >>= 1) zm = fmaxf(zm, __shfl_xor(zm, off, 16));
        float p = expf(z - zm);
        float ps = p;
        for (int off = 8; off; off >>= 1) ps += __shfl_xor(ps, off, 16);
        sAttn[r * 16 + m] = p / ps;
    }
    __syncthreads();

    // sampled = memory^T @ attn + 1
#pragma unroll
    for (int q = 0; q < 4; ++q) {
        int r = w * 4 + q;
        const float* mem = memory + (size_t)(b0 + r) * 1024 + l;
        float s = 0.f;
#pragma unroll
        for (int m = 0; m < 16; ++m) s += sAttn[r * 16 + m] * mem[m * 64];
        sSamp[r * 64 + l] = s + 1.0f;
    }
    __syncthreads();

    // alpha / beta
    {
        int r = t >> 4, s16 = t & 15;
        size_t hoff = (size_t)(b0 + r) * 2050;
        size_t xoff = (size_t)(b0 + r) * 1024;
        float za = 0.f, zb = 0.f;
        for (int kk = 0; kk < 64; ++kk) {
            int k = s16 + kk * 16;  // coalesced within 16-lane group
            float hv = outr[hoff + k];
            float xv = x[xoff + k];
            za += hv * w_a_h[k] + xv * w_a_x[k];
            zb += hv * w_b_h[k] + xv * w_b_x[k];
        }
#pragma unroll
        for (int k = s16 * 4; k < s16 * 4 + 4; ++k) {
            float sv = sSamp[r * 64 + k];
            za += sv * w_a_r[k];
            zb += sv * w_b_r[k];
        }
        for (int off = 8; off; off >>= 1) {
            za += __shfl_xor(za, off, 16);
            zb += __shfl_xor(zb, off, 16);
        }
        if (s16 == 0) {
            float ua = u_a[b0 + r];
            float ub = u_b[b0 + r];
            float la = logf(ua) - log1pf(-ua);
            float lb = logf(ub) - log1pf(-ub);
            out[(size_t)(b0 + r) * 2050 + 2048] = sigmoidf_(za + la);
            out[(size_t)(b0 + r) * 2050 + 2049] = sigmoidf_(zb + lb);
        }
    }
}

extern "C" void kernel_launch(void* const* d_in, const int* in_sizes, int n_in,
                              void* d_out, int out_size, void* d_ws, size_t ws_size,
                              hipStream_t stream) {
    const float* x      = (const float*)d_in[0];
    const float* h      = (const float*)d_in[1];
    const float* c      = (const float*)d_in[2];
    const float* memory = (const float*)d_in[3];
    const float* u_gs   = (const float*)d_in[4];
    const float* u_a    = (const float*)d_in[5];
    const float* u_b    = (const float*)d_in[6];
    const float* W_i    = (const float*)d_in[7];
    const float* b_i    = (const float*)d_in[8];
    const float* W_f    = (const float*)d_in[9];
    const float* b_f    = (const float*)d_in[10];
    const float* W_o    = (const float*)d_in[11];
    const float* b_o    = (const float*)d_in[12];
    const float* W_cand = (const float*)d_in[13];
    const float* b_cand = (const float*)d_in[14];
    const float* W_m    = (const float*)d_in[15];
    const float* b_m    = (const float*)d_in[16];
    const float* w_a_h  = (const float*)d_in[17];
    const float* w_a_x  = (const float*)d_in[18];
    const float* w_a_r  = (const float*)d_in[19];
    const float* w_b_h  = (const float*)d_in[20];
    const float* w_b_x  = (const float*)d_in[21];
    const float* w_b_r  = (const float*)d_in[22];
    float* out = (float*)d_out;

    // workspace carve (bytes)
    char* ws = (char*)d_ws;
    ushort* WT    = (ushort*)(ws);                 // 25,165,824
    ushort* WoCT  = (ushort*)(ws + 25165824);      //  2,097,152
    ushort* Pre   = (ushort*)(ws + 27262976);      // 67,108,864
    ushort* xhcb  = (ushort*)(ws + 94371840);      // 50,331,648
    float*  Biasf = (float*)(ws + 144703488);      //     16,384
    ushort* WmT   = (ushort*)(ws + 144719872);     //    131,072
    ushort* Cnewb = xhcb;                          // alias: xhcb dead after k_gemm1
    ushort* Hnewb = WT;                            // alias: WT dead after k_gemm1 (16.8M < 25.2M)

    k_castcat<<<12288, 256, 0, stream>>>(x, h, c, xhcb);

    TA ta;
    ta.d[0] = {W_i,                      WT,                        1024, 3072, 48, 0};
    ta.d[1] = {W_f,                      WT + (size_t)1024 * 3072,  1024, 3072, 48, 768};
    ta.d[2] = {W_cand,                   WT + (size_t)2048 * 3072,  1024, 3072, 32, 1536};
    ta.d[3] = {W_o,                      WT + (size_t)3072 * 3072,  1024, 3072, 48, 2048};
    ta.d[4] = {W_o + (size_t)2048 * 1024, WoCT,                     1024, 1024, 16, 2816};
    ta.d[5] = {W_m,                      WmT,                         64, 1024, 16, 3072};
    k_transAll<<<3088, 256, 0, stream>>>(ta);
    k_biasf<<<16, 256, 0, stream>>>(b_i, b_f, b_cand, b_o, Biasf);

    k_gemm1<<<dim3(64, 32), 256, 0, stream>>>(xhcb, WT, Biasf, Pre);
    k_cnew<<<4096, 256, 0, stream>>>(Pre, c, Cnewb, out);
    k_gemm2<<<dim3(64, 8), 256, 0, stream>>>(Cnewb, WoCT, Pre, Hnewb, out);
    k_attn<<<512, 256, 0, stream>>>(Hnewb, out, x, memory, u_gs, u_a, u_b, WmT, b_m,
                                    w_a_h, w_a_x, w_a_r, w_b_h, w_b_x, w_b_r, out);
}

// Round 4
// 515.894 us; speedup vs baseline: 1.1250x; 1.1088x over previous
//
#include <hip/hip_runtime.h>

typedef __bf16 bfrag __attribute__((ext_vector_type(8)));
typedef float f32x4 __attribute__((ext_vector_type(4)));

#define GLDS16(g, l) __builtin_amdgcn_global_load_lds( \
    (__attribute__((address_space(1))) void*)(g),      \
    (__attribute__((address_space(3))) void*)(l), 16, 0, 0)

__device__ __forceinline__ float bf2f(ushort u) {
    return __uint_as_float(((unsigned)u) << 16);
}
__device__ __forceinline__ ushort f2bf(float f) {
    unsigned u = __float_as_uint(f);
    u += 0x7fff + ((u >> 16) & 1);
    return (ushort)(u >> 16);
}
__device__ __forceinline__ float sigmoidf_(float v) {
    return 1.0f / (1.0f + expf(-v));
}

// ---------------- merged prep: castcat + all transposes + bias concat ----------------
struct TD { const float* src; ushort* dst; int src_ld; int dst_ld; int ktiles; int off; };
struct TA { TD d[6]; };

__global__ __launch_bounds__(256) void k_prep(const float* __restrict__ x,
                                              const float* __restrict__ h,
                                              const float* __restrict__ c,
                                              ushort* __restrict__ xhcb, TA a,
                                              const float* __restrict__ bi,
                                              const float* __restrict__ bf_,
                                              const float* __restrict__ bc,
                                              const float* __restrict__ bo,
                                              float* __restrict__ Biasf) {
    __shared__ float tile[64][65];
    int bid = blockIdx.x;
    int t = threadIdx.x;
    if (bid < 12288) {
        // castcat: xhcb[b][0:3072] = bf16([x|h|c][b]), 8 elems/thread
        int idx = bid * 256 + t;
        int row = idx / 384;
        int c8 = (idx - row * 384) * 8;
        const float* s = (c8 < 1024) ? &x[(size_t)row * 1024 + c8]
                       : (c8 < 2048) ? &h[(size_t)row * 1024 + (c8 - 1024)]
                                     : &c[(size_t)row * 1024 + (c8 - 2048)];
        float4 va = *(const float4*)s;
        float4 vb = *(const float4*)(s + 4);
        ushort tmp[8] = {f2bf(va.x), f2bf(va.y), f2bf(va.z), f2bf(va.w),
                         f2bf(vb.x), f2bf(vb.y), f2bf(vb.z), f2bf(vb.w)};
        *(uint4*)&xhcb[(size_t)idx * 8] = *(uint4*)tmp;
    } else if (bid < 15120) {
        // transpose+cast: dst[n*dst_ld + k] = bf16(src[k*src_ld + n])
        int tb = bid - 12288;
        int ri = 0;
#pragma unroll
        for (int i = 1; i < 6; ++i) ri = (tb >= a.d[i].off) ? i : ri;
        const float* src = a.d[ri].src;
        ushort* dst = a.d[ri].dst;
        int src_ld = a.d[ri].src_ld, dst_ld = a.d[ri].dst_ld;
        int local = tb - a.d[ri].off;
        int bx = local % a.d[ri].ktiles;
        int by = local / a.d[ri].ktiles;
        int k0 = bx * 64, n0 = by * 64;
        int c4 = (t & 15) * 4;
        int r = t >> 4;
#pragma unroll
        for (int i = 0; i < 4; ++i) {
            int rr = r + i * 16;
            float4 v = *(const float4*)&src[(size_t)(k0 + rr) * src_ld + n0 + c4];
            tile[rr][c4 + 0] = v.x; tile[rr][c4 + 1] = v.y;
            tile[rr][c4 + 2] = v.z; tile[rr][c4 + 3] = v.w;
        }
        __syncthreads();
        int kk8 = (t & 7) * 8;
        int nn = t >> 3;
#pragma unroll
        for (int i = 0; i < 2; ++i) {
            int n = nn + i * 32;
            ushort tmp[8];
#pragma unroll
            for (int j = 0; j < 8; ++j) tmp[j] = f2bf(tile[kk8 + j][n]);
            *(uint4*)&dst[(size_t)(n0 + n) * dst_ld + k0 + kk8] = *(uint4*)tmp;
        }
    } else {
        int idx = (bid - 15120) * 256 + t;  // 0..4095
        int g = idx >> 10, n = idx & 1023;
        const float* s = (g == 0) ? bi : (g == 1) ? bf_ : (g == 2) ? bc : bo;
        Biasf[idx] = s[n];
    }
}

// ---------------- GEMM1 (templated K): Pre[:, nbase:nbase+2048] ----------------
// BK=64; LDS slot swizzle: 16B group kg stored at slot kg ^ (row & 7).
template <int KTOT>
__global__ __launch_bounds__(256) void k_gemm1t(const ushort* __restrict__ xhcb,
                                                const ushort* __restrict__ WT,
                                                const float* __restrict__ bias,
                                                ushort* __restrict__ Pre, int nbase) {
    __shared__ __align__(16) ushort As[128 * 64];
    __shared__ __align__(16) ushort Bs[128 * 64];
    int t = threadIdx.x;
    int m0 = blockIdx.x * 128, n0 = nbase + blockIdx.y * 128;
    int w = t >> 6, l = t & 63;
    int wm = (w & 1) * 64, wn = (w >> 1) * 64;
    int lane16 = l & 15, quad = l >> 4;
    int rowt = t >> 3;                       // 0..31 staging row within 32-chunk
    int kg = (t & 7) ^ (rowt & 7);           // swizzled source 16B-group
    int r7 = lane16 & 7;                     // read-side swizzle key
    f32x4 acc[4][4] = {};

    const ushort* Abase = xhcb + (size_t)(m0 + rowt) * 3072 + kg * 8;
    const ushort* Bbase = WT + (size_t)(n0 + rowt) * 3072 + kg * 8;

    for (int k0 = 0; k0 < KTOT; k0 += 64) {
#pragma unroll
        for (int q = 0; q < 4; ++q)
            GLDS16(Abase + (size_t)q * 32 * 3072 + k0, As + q * 2048 + t * 8);
#pragma unroll
        for (int q = 0; q < 4; ++q)
            GLDS16(Bbase + (size_t)q * 32 * 3072 + k0, Bs + q * 2048 + t * 8);
        __syncthreads();
#pragma unroll
        for (int hh = 0; hh < 2; ++hh) {
            int slot8 = ((hh * 4 + quad) ^ r7) * 8;
            bfrag af[4], bfr[4];
#pragma unroll
            for (int i = 0; i < 4; ++i) {
                af[i]  = *(const bfrag*)&As[(wm + i * 16 + lane16) * 64 + slot8];
                bfr[i] = *(const bfrag*)&Bs[(wn + i * 16 + lane16) * 64 + slot8];
            }
#pragma unroll
            for (int i = 0; i < 4; ++i)
#pragma unroll
                for (int j = 0; j < 4; ++j)
                    acc[i][j] = __builtin_amdgcn_mfma_f32_16x16x32_bf16(af[i], bfr[j], acc[i][j], 0, 0, 0);
        }
        __syncthreads();
    }
#pragma unroll
    for (int i = 0; i < 4; ++i) {
#pragma unroll
        for (int j = 0; j < 4; ++j) {
            int col = n0 + wn + j * 16 + lane16;
            float bv = bias[col];
            int rbase = m0 + wm + i * 16 + quad * 4;
#pragma unroll
            for (int r = 0; r < 4; ++r)
                Pre[(size_t)(rbase + r) * 4096 + col] = f2bf(acc[i][j][r] + bv);
        }
    }
}

// ---------------- c_new = sigmoid(f)*c + sigmoid(i)*tanh(cand) ----------------
__global__ __launch_bounds__(256) void k_cnew(const ushort* __restrict__ Pre,
                                              const float* __restrict__ cin,
                                              ushort* __restrict__ Cnewb,
                                              float* __restrict__ out) {
    int idx8 = blockIdx.x * 256 + threadIdx.x;  // 1,048,576 total
    int b = idx8 >> 7;
    int n8 = (idx8 & 127) * 8;
    uint4 vi = *(const uint4*)(Pre + (size_t)b * 4096 + n8);
    uint4 vf = *(const uint4*)(Pre + (size_t)b * 4096 + 1024 + n8);
    uint4 vc = *(const uint4*)(Pre + (size_t)b * 4096 + 2048 + n8);
    float4 c0 = *(const float4*)(cin + (size_t)b * 1024 + n8);
    float4 c1 = *(const float4*)(cin + (size_t)b * 1024 + n8 + 4);
    const ushort* pi = (const ushort*)&vi;
    const ushort* pf = (const ushort*)&vf;
    const ushort* pc = (const ushort*)&vc;
    float cv[8] = {c0.x, c0.y, c0.z, c0.w, c1.x, c1.y, c1.z, c1.w};
    float cn[8];
    ushort cb[8];
#pragma unroll
    for (int j = 0; j < 8; ++j) {
        float iv = sigmoidf_(bf2f(pi[j]));
        float fv = sigmoidf_(bf2f(pf[j]));
        float cp = tanhf(bf2f(pc[j]));
        cn[j] = fv * cv[j] + iv * cp;
        cb[j] = f2bf(cn[j]);
    }
    *(uint4*)(Cnewb + (size_t)b * 1024 + n8) = *(uint4*)cb;
    float* orow = out + (size_t)b * 2050 + 1024 + n8;  // 8B-aligned
#pragma unroll
    for (int j = 0; j < 4; ++j)
        *(float2*)(orow + j * 2) = make_float2(cn[j * 2], cn[j * 2 + 1]);
}

// ---------------- GEMM2: o_pre = Pre_o + c_new @ W_o[2048:]; h_new = sig(o)*tanh(c_new)
__global__ __launch_bounds__(256) void k_gemm2(const ushort* __restrict__ Cnewb,
                                               const ushort* __restrict__ WoCT,
                                               const ushort* __restrict__ Pre,
                                               ushort* __restrict__ Hnewb,
                                               float* __restrict__ out) {
    __shared__ __align__(16) ushort As[128 * 64];
    __shared__ __align__(16) ushort Bs[128 * 64];
    int t = threadIdx.x;
    int m0 = blockIdx.x * 128, n0 = blockIdx.y * 128;
    int w = t >> 6, l = t & 63;
    int wm = (w & 1) * 64, wn = (w >> 1) * 64;
    int lane16 = l & 15, quad = l >> 4;
    int rowt = t >> 3;
    int kg = (t & 7) ^ (rowt & 7);
    int r7 = lane16 & 7;
    f32x4 acc[4][4] = {};

    const ushort* Abase = Cnewb + (size_t)(m0 + rowt) * 1024 + kg * 8;
    const ushort* Bbase = WoCT + (size_t)(n0 + rowt) * 1024 + kg * 8;

    for (int k0 = 0; k0 < 1024; k0 += 64) {
#pragma unroll
        for (int q = 0; q < 4; ++q)
            GLDS16(Abase + (size_t)q * 32 * 1024 + k0, As + q * 2048 + t * 8);
#pragma unroll
        for (int q = 0; q < 4; ++q)
            GLDS16(Bbase + (size_t)q * 32 * 1024 + k0, Bs + q * 2048 + t * 8);
        __syncthreads();
#pragma unroll
        for (int hh = 0; hh < 2; ++hh) {
            int slot8 = ((hh * 4 + quad) ^ r7) * 8;
            bfrag af[4], bfr[4];
#pragma unroll
            for (int i = 0; i < 4; ++i) {
                af[i]  = *(const bfrag*)&As[(wm + i * 16 + lane16) * 64 + slot8];
                bfr[i] = *(const bfrag*)&Bs[(wn + i * 16 + lane16) * 64 + slot8];
            }
#pragma unroll
            for (int i = 0; i < 4; ++i)
#pragma unroll
                for (int j = 0; j < 4; ++j)
                    acc[i][j] = __builtin_amdgcn_mfma_f32_16x16x32_bf16(af[i], bfr[j], acc[i][j], 0, 0, 0);
        }
        __syncthreads();
    }
#pragma unroll
    for (int i = 0; i < 4; ++i) {
#pragma unroll
        for (int j = 0; j < 4; ++j) {
            int col = n0 + wn + j * 16 + lane16;
            int rbase = m0 + wm + i * 16 + quad * 4;
#pragma unroll
            for (int r = 0; r < 4; ++r) {
                int row = rbase + r;
                float opre = acc[i][j][r] + bf2f(Pre[(size_t)row * 4096 + 3072 + col]);
                float o = sigmoidf_(opre);
                float cnv = bf2f(Cnewb[(size_t)row * 1024 + col]);
                float hv = o * tanhf(cnv);
                Hnewb[(size_t)row * 1024 + col] = f2bf(hv);
                out[(size_t)row * 2050 + col] = hv;
            }
        }
    }
}

// ---------------- attention + gumbel + alpha/beta (16 rows per block) ----------------
__global__ __launch_bounds__(256) void k_attn(
    const ushort* __restrict__ Hnewb, const float* __restrict__ outr,
    const float* __restrict__ x, const float* __restrict__ memory,
    const float* __restrict__ u_gs, const float* __restrict__ u_a,
    const float* __restrict__ u_b, const ushort* __restrict__ WmT,
    const float* __restrict__ b_m,
    const float* __restrict__ w_a_h, const float* __restrict__ w_a_x,
    const float* __restrict__ w_a_r, const float* __restrict__ w_b_h,
    const float* __restrict__ w_b_x, const float* __restrict__ w_b_r,
    float* __restrict__ out) {
    __shared__ float sMicro[16 * 64];
    __shared__ float sAttn[16 * 16];
    __shared__ float sSamp[16 * 64];

    int b0 = blockIdx.x * 16;
    int t = threadIdx.x;
    int w = t >> 6, l = t & 63;
    int lane16 = l & 15, quad = l >> 4;

    // wave w computes micro[0:16][16w:16w+16] via MFMA
    {
        f32x4 acc = {0.f, 0.f, 0.f, 0.f};
        const ushort* Ab = Hnewb + (size_t)(b0 + lane16) * 1024 + quad * 8;
        const ushort* Bb = WmT + (size_t)(w * 16 + lane16) * 1024 + quad * 8;
#pragma unroll 4
        for (int k0 = 0; k0 < 1024; k0 += 32) {
            bfrag av = *(const bfrag*)(Ab + k0);
            bfrag bv = *(const bfrag*)(Bb + k0);
            acc = __builtin_amdgcn_mfma_f32_16x16x32_bf16(av, bv, acc, 0, 0, 0);
        }
        float bm = b_m[w * 16 + lane16];
#pragma unroll
        for (int r = 0; r < 4; ++r)
            sMicro[(quad * 4 + r) * 64 + w * 16 + lane16] = acc[r] + bm;
    }
    __syncthreads();

    // logits + gumbel softmax over M=16
    {
        int r = t >> 4, m = t & 15;
        const float4* mem4 = (const float4*)(memory + (size_t)(b0 + r) * 1024 + m * 64);
        float lg = 0.f;
#pragma unroll
        for (int k4 = 0; k4 < 16; ++k4) {
            float4 mv = mem4[k4];
            const float* sm = &sMicro[r * 64 + k4 * 4];
            lg += mv.x * sm[0] + mv.y * sm[1] + mv.z * sm[2] + mv.w * sm[3];
        }
        float u = u_gs[(b0 + r) * 16 + m];
        float z = lg - logf(-logf(u));  // TAU = 1
        float zm = z;
        for (int off = 8; off; off >>= 1) zm = fmaxf(zm, __shfl_xor(zm, off, 16));
        float p = expf(z - zm);
        float ps = p;
        for (int off = 8; off; off >>= 1) ps += __shfl_xor(ps, off, 16);
        sAttn[r * 16 + m] = p / ps;
    }
    __syncthreads();

    // sampled = memory^T @ attn + 1
#pragma unroll
    for (int q = 0; q < 4; ++q) {
        int r = w * 4 + q;
        const float* mem = memory + (size_t)(b0 + r) * 1024 + l;
        float s = 0.f;
#pragma unroll
        for (int m = 0; m < 16; ++m) s += sAttn[r * 16 + m] * mem[m * 64];
        sSamp[r * 64 + l] = s + 1.0f;
    }
    __syncthreads();

    // alpha / beta
    {
        int r = t >> 4, s16 = t & 15;
        size_t hoff = (size_t)(b0 + r) * 2050;
        size_t xoff = (size_t)(b0 + r) * 1024;
        float za = 0.f, zb = 0.f;
        for (int kk = 0; kk < 64; ++kk) {
            int k = s16 + kk * 16;
            float hv = outr[hoff + k];
            float xv = x[xoff + k];
            za += hv * w_a_h[k] + xv * w_a_x[k];
            zb += hv * w_b_h[k] + xv * w_b_x[k];
        }
#pragma unroll
        for (int k = s16 * 4; k < s16 * 4 + 4; ++k) {
            float sv = sSamp[r * 64 + k];
            za += sv * w_a_r[k];
            zb += sv * w_b_r[k];
        }
        for (int off = 8; off; off >>= 1) {
            za += __shfl_xor(za, off, 16);
            zb += __shfl_xor(zb, off, 16);
        }
        if (s16 == 0) {
            float ua = u_a[b0 + r];
            float ub = u_b[b0 + r];
            float la = logf(ua) - log1pf(-ua);
            float lb = logf(ub) - log1pf(-ub);
            out[(size_t)(b0 + r) * 2050 + 2048] = sigmoidf_(za + la);
            out[(size_t)(b0 + r) * 2050 + 2049] = sigmoidf_(zb + lb);
        }
    }
}

extern "C" void kernel_launch(void* const* d_in, const int* in_sizes, int n_in,
                              void* d_out, int out_size, void* d_ws, size_t ws_size,
                              hipStream_t stream) {
    const float* x      = (const float*)d_in[0];
    const float* h      = (const float*)d_in[1];
    const float* c      = (const float*)d_in[2];
    const float* memory = (const float*)d_in[3];
    const float* u_gs   = (const float*)d_in[4];
    const float* u_a    = (const float*)d_in[5];
    const float* u_b    = (const float*)d_in[6];
    const float* W_i    = (const float*)d_in[7];
    const float* b_i    = (const float*)d_in[8];
    const float* W_f    = (const float*)d_in[9];
    const float* b_f    = (const float*)d_in[10];
    const float* W_o    = (const float*)d_in[11];
    const float* b_o    = (const float*)d_in[12];
    const float* W_cand = (const float*)d_in[13];
    const float* b_cand = (const float*)d_in[14];
    const float* W_m    = (const float*)d_in[15];
    const float* b_m    = (const float*)d_in[16];
    const float* w_a_h  = (const float*)d_in[17];
    const float* w_a_x  = (const float*)d_in[18];
    const float* w_a_r  = (const float*)d_in[19];
    const float* w_b_h  = (const float*)d_in[20];
    const float* w_b_x  = (const float*)d_in[21];
    const float* w_b_r  = (const float*)d_in[22];
    float* out = (float*)d_out;

    // workspace carve (bytes)
    char* ws = (char*)d_ws;
    ushort* WT    = (ushort*)(ws);                 // 25,165,824
    ushort* WoCT  = (ushort*)(ws + 25165824);      //  2,097,152
    ushort* Pre   = (ushort*)(ws + 27262976);      // 67,108,864
    ushort* xhcb  = (ushort*)(ws + 94371840);      // 50,331,648
    float*  Biasf = (float*)(ws + 144703488);      //     16,384
    ushort* WmT   = (ushort*)(ws + 144719872);     //    131,072
    ushort* Cnewb = xhcb;                          // alias: xhcb dead after gemm1
    ushort* Hnewb = WT;                            // alias: WT dead after gemm1

    TA ta;
    ta.d[0] = {W_i,                       WT,                        1024, 3072, 48, 0};
    ta.d[1] = {W_f,                       WT + (size_t)1024 * 3072,  1024, 3072, 48, 768};
    ta.d[2] = {W_cand,                    WT + (size_t)2048 * 3072,  1024, 3072, 32, 1536};
    ta.d[3] = {W_o,                       WT + (size_t)3072 * 3072,  1024, 3072, 32, 2048};  // first 2048 rows used
    ta.d[4] = {W_o + (size_t)2048 * 1024, WoCT,                      1024, 1024, 16, 2560};
    ta.d[5] = {W_m,                       WmT,                         64, 1024, 16, 2816};  // 16 blocks only

    k_prep<<<15136, 256, 0, stream>>>(x, h, c, xhcb, ta, b_i, b_f, b_cand, b_o, Biasf);

    k_gemm1t<3072><<<dim3(64, 16), 256, 0, stream>>>(xhcb, WT, Biasf, Pre, 0);
    k_gemm1t<2048><<<dim3(64, 16), 256, 0, stream>>>(xhcb, WT, Biasf, Pre, 2048);
    k_cnew<<<4096, 256, 0, stream>>>(Pre, c, Cnewb, out);
    k_gemm2<<<dim3(64, 8), 256, 0, stream>>>(Cnewb, WoCT, Pre, Hnewb, out);
    k_attn<<<512, 256, 0, stream>>>(Hnewb, out, x, memory, u_gs, u_a, u_b, WmT, b_m,
                                    w_a_h, w_a_x, w_a_r, w_b_h, w_b_x, w_b_r, out);
}